// Round 1
// baseline (430.871 us; speedup 1.0000x reference)
//
#include <hip/hip_runtime.h>

// Problem constants (fixed by the reference):
//   D=128 fine grid, CD=64 coarse grid, CIN=16, COUT=32, K=2, S=2, B=2
// h layout (workspace): [b][mz][my][mx][ic]  -> ((b<<18 | mz<<12 | my<<6 | mx)<<5 | ic)
// size = 2 * 64^3 * 32 floats = 64 MiB

#define NPT_CH_SCATTER 32   // one thread per (point, ic)
#define NPT_CH_GATHER  16   // one thread per (point, oc)

__global__ __launch_bounds__(256) void scn_scatter_conv1(
    const float* __restrict__ feat, const float* __restrict__ W1,
    const int* __restrict__ coors, float* __restrict__ h, int npts)
{
    // Stage W1 transposed: Ws[parity][cin][ic], lane-varying ic is stride-1.
    __shared__ float Ws[8 * 16 * 32];
    for (int i = threadIdx.x; i < 4096; i += 256) {
        // W1 global layout: [ic:32][cin:16][kz][ky][kx] = ic*128 + cin*8 + p
        int ic = i >> 7, rem = i & 127, cin = rem >> 3, p = rem & 7;
        Ws[(p << 9) | (cin << 5) | ic] = W1[i];
    }
    __syncthreads();

    int total = npts * NPT_CH_SCATTER;
    for (int idx = blockIdx.x * 256 + threadIdx.x; idx < total;
         idx += gridDim.x * 256) {
        int pid = idx >> 5, ic = idx & 31;
        int b = coors[pid * 4 + 0];
        int z = coors[pid * 4 + 1];
        int y = coors[pid * 4 + 2];
        int x = coors[pid * 4 + 3];
        int p = ((z & 1) << 2) | ((y & 1) << 1) | (x & 1);

        const float4* f4 = reinterpret_cast<const float4*>(feat + pid * 16);
        float4 a0 = f4[0], a1 = f4[1], a2 = f4[2], a3 = f4[3];

        const float* w = Ws + (p << 9) + ic;   // stride 32 over cin
        float s = 0.f;
        s += a0.x * w[0 << 5];  s += a0.y * w[1 << 5];
        s += a0.z * w[2 << 5];  s += a0.w * w[3 << 5];
        s += a1.x * w[4 << 5];  s += a1.y * w[5 << 5];
        s += a1.z * w[6 << 5];  s += a1.w * w[7 << 5];
        s += a2.x * w[8 << 5];  s += a2.y * w[9 << 5];
        s += a2.z * w[10 << 5]; s += a2.w * w[11 << 5];
        s += a3.x * w[12 << 5]; s += a3.y * w[13 << 5];
        s += a3.z * w[14 << 5]; s += a3.w * w[15 << 5];

        int cell = (b << 18) | ((z >> 1) << 12) | ((y >> 1) << 6) | (x >> 1);
        atomicAdd(&h[((size_t)cell << 5) | ic], s);
    }
}

__global__ __launch_bounds__(256) void scn_gather_deconv2(
    const float* __restrict__ h, const float* __restrict__ W2,
    const int* __restrict__ coors, float* __restrict__ out, int npts)
{
    // Stage W2 transposed: Ws[parity][ic][oc], lane-varying oc is stride-1.
    __shared__ float Ws[8 * 32 * 16];
    for (int i = threadIdx.x; i < 4096; i += 256) {
        // W2 global layout: [oc:16][ic:32][kz][ky][kx] = oc*256 + ic*8 + p
        int oc = i >> 8, rem = i & 255, ic = rem >> 3, p = rem & 7;
        Ws[(p << 9) | (ic << 4) | oc] = W2[i];
    }
    __syncthreads();

    int total = npts * NPT_CH_GATHER;
    for (int idx = blockIdx.x * 256 + threadIdx.x; idx < total;
         idx += gridDim.x * 256) {
        int pid = idx >> 4, oc = idx & 15;
        int b = coors[pid * 4 + 0];
        int z = coors[pid * 4 + 1];
        int y = coors[pid * 4 + 2];
        int x = coors[pid * 4 + 3];
        // deconv picks the tap where the dilated index is even: (d&1)^1
        int p = (((z & 1) ^ 1) << 2) | (((y & 1) ^ 1) << 1) | ((x & 1) ^ 1);

        int cell = (b << 18) | ((z >> 1) << 12) | ((y >> 1) << 6) | (x >> 1);
        const float4* h4 = reinterpret_cast<const float4*>(h + ((size_t)cell << 5));
        float4 h0 = h4[0], h1 = h4[1], h2 = h4[2], h3 = h4[3];
        float4 h5 = h4[4], h6 = h4[5], h7 = h4[6], h8 = h4[7];

        const float* w = Ws + (p << 9) + oc;   // stride 16 over ic
        float s = 0.f;
        s += h0.x * w[0 << 4];   s += h0.y * w[1 << 4];
        s += h0.z * w[2 << 4];   s += h0.w * w[3 << 4];
        s += h1.x * w[4 << 4];   s += h1.y * w[5 << 4];
        s += h1.z * w[6 << 4];   s += h1.w * w[7 << 4];
        s += h2.x * w[8 << 4];   s += h2.y * w[9 << 4];
        s += h2.z * w[10 << 4];  s += h2.w * w[11 << 4];
        s += h3.x * w[12 << 4];  s += h3.y * w[13 << 4];
        s += h3.z * w[14 << 4];  s += h3.w * w[15 << 4];
        s += h5.x * w[16 << 4];  s += h5.y * w[17 << 4];
        s += h5.z * w[18 << 4];  s += h5.w * w[19 << 4];
        s += h6.x * w[20 << 4];  s += h6.y * w[21 << 4];
        s += h6.z * w[22 << 4];  s += h6.w * w[23 << 4];
        s += h7.x * w[24 << 4];  s += h7.y * w[25 << 4];
        s += h7.z * w[26 << 4];  s += h7.w * w[27 << 4];
        s += h8.x * w[28 << 4];  s += h8.y * w[29 << 4];
        s += h8.z * w[30 << 4];  s += h8.w * w[31 << 4];

        // out[b][oc][z][y][x], fine grid 128^3
        size_t oidx = (size_t)(b * 16 + oc) * 2097152 + (size_t)z * 16384
                    + (size_t)y * 128 + (size_t)x;
        out[oidx] = s;
    }
}

extern "C" void kernel_launch(void* const* d_in, const int* in_sizes, int n_in,
                              void* d_out, int out_size, void* d_ws, size_t ws_size,
                              hipStream_t stream) {
    const float* feat  = (const float*)d_in[0];
    const float* W1    = (const float*)d_in[1];
    const float* W2    = (const float*)d_in[2];
    const int*   coors = (const int*)d_in[3];
    float*       out   = (float*)d_out;
    float*       h     = (float*)d_ws;
    int npts = in_sizes[0] / 16;

    const size_t h_bytes = (size_t)2 * 262144 * 32 * sizeof(float);  // 64 MiB

    // Output is mask*dec: zero everywhere except occupied voxels.
    hipMemsetAsync(d_out, 0, (size_t)out_size * sizeof(float), stream);
    // h must start at zero for the atomic scatter.
    hipMemsetAsync(d_ws, 0, h_bytes, stream);

    int t1 = npts * NPT_CH_SCATTER;
    int blocks1 = (t1 + 255) / 256;
    if (blocks1 > 4096) blocks1 = 4096;
    scn_scatter_conv1<<<blocks1, 256, 0, stream>>>(feat, W1, coors, h, npts);

    int t2 = npts * NPT_CH_GATHER;
    int blocks2 = (t2 + 255) / 256;
    if (blocks2 > 4096) blocks2 = 4096;
    scn_gather_deconv2<<<blocks2, 256, 0, stream>>>(h, W2, coors, out, npts);
}